// Round 5
// baseline (67.767 us; speedup 1.0000x reference)
//
#include <hip/hip_runtime.h>

#define VOCAB 100000
#define DIM 128
#define BATCH 65536
#define NEG 5

#define TPB 256
#define WAVES 4
#define BLOCKS 2048
#define ITERS 4                 // 2 elements per slot, 4 slots per wave -> 8 elem/wave
#define SLOT_BYTES 7168         // 14 rows * 512 B
#define ROWB 512

typedef __attribute__((address_space(1))) void gvoid;
typedef __attribute__((address_space(3))) void lvoid;

__device__ __forceinline__ float log_sigmoid(float x) {
    return fminf(x, 0.0f) - log1pf(expf(-fabsf(x)));
}
__device__ __forceinline__ float dot4(float4 a, float4 b) {
    return a.x * b.x + a.y * b.y + a.z * b.z + a.w * b.w;
}
__device__ __forceinline__ void gload_lds16(const void* g, void* l) {
    __builtin_amdgcn_global_load_lds((gvoid*)g, (lvoid*)l, 16, 0, 0);
}

// issue 7 x 1KB global_load_lds for slot `it` (wave-uniform LDS dest, per-lane src)
#define ISSUE_SLOT(it)                                                         \
    {                                                                          \
        char* dst = mybuf + ((it) & 1) * SLOT_BYTES;                           \
        _Pragma("unroll")                                                      \
        for (int j = 0; j < 7; ++j) {                                          \
            const int r = half ? rows[it][2 * j + 1] : rows[it][2 * j];        \
            const float* tb =                                                  \
                ((j == 0 && half) || (j == 4 && !half)) ? W_ctx : W_in;        \
            const char* src = (const char*)(tb + (size_t)r * DIM) + l32 * 16;  \
            gload_lds16(src, dst + j * 1024);                                  \
        }                                                                      \
    }

#define COMPUTE_SLOT(it)                                                       \
    {                                                                          \
        const char* base =                                                     \
            mybuf + ((it) & 1) * SLOT_BYTES + half * 3584 + l32 * 16;          \
        const float4 ei = *(const float4*)(base + 0 * ROWB);                   \
        const float4 ec = *(const float4*)(base + 1 * ROWB);                   \
        float pos_s = dot4(ei, ec);                                            \
        float nd[NEG];                                                         \
        _Pragma("unroll")                                                      \
        for (int k = 0; k < NEG; ++k) {                                        \
            const float4 en = *(const float4*)(base + (2 + k) * ROWB);         \
            nd[k] = dot4(en, ei);                                              \
        }                                                                      \
        _Pragma("unroll")                                                      \
        for (int m = 1; m <= 16; m <<= 1) {                                    \
            pos_s += __shfl_xor(pos_s, m);                                     \
            _Pragma("unroll")                                                  \
            for (int k = 0; k < NEG; ++k) nd[k] += __shfl_xor(nd[k], m);       \
        }                                                                      \
        if (l32 == 0) {                                                        \
            float loss = log_sigmoid(pos_s);                                   \
            _Pragma("unroll")                                                  \
            for (int k = 0; k < NEG; ++k) loss += log_sigmoid(-nd[k]);         \
            acc += loss;                                                       \
        }                                                                      \
    }

#define WAITV(n)                                                               \
    asm volatile("s_waitcnt vmcnt(" #n ")" ::: "memory");                      \
    __builtin_amdgcn_sched_barrier(0);

#define FENCE() __builtin_amdgcn_sched_barrier(0);

__global__ __launch_bounds__(TPB) void g2v_partial(
    const float* __restrict__ W_in, const float* __restrict__ W_ctx,
    const int* __restrict__ input_word, const int* __restrict__ context_word,
    const int* __restrict__ neg_idx, float* __restrict__ block_sums)
{
    __shared__ __align__(16) char ldsraw[WAVES * 2 * SLOT_BYTES];
    __shared__ float swave[WAVES];

    const int tid = threadIdx.x;
    const int wid = tid >> 6;
    const int lane = tid & 63;
    const int half = lane >> 5;
    const int l32 = lane & 31;
    const int gw = blockIdx.x * WAVES + wid;

    char* mybuf = ldsraw + wid * (2 * SLOT_BYTES);

    // ---- load ALL 56 row indices for this wave's 4 slots (static indexing) ----
    int rows[ITERS][14];
    #pragma unroll
    for (int it = 0; it < ITERS; ++it) {
        const int b0 = (gw * ITERS + it) * 2;
        rows[it][0] = input_word[b0];
        rows[it][1] = context_word[b0];
        #pragma unroll
        for (int k = 0; k < NEG; ++k) rows[it][2 + k] = neg_idx[b0 * NEG + k];
        rows[it][7] = input_word[b0 + 1];
        rows[it][8] = context_word[b0 + 1];
        #pragma unroll
        for (int k = 0; k < NEG; ++k) rows[it][9 + k] = neg_idx[(b0 + 1) * NEG + k];
    }
    // full drain: from here on, vmcnt tracks ONLY global_load_lds ops
    asm volatile("s_waitcnt vmcnt(0)" ::: "memory");
    __builtin_amdgcn_sched_barrier(0);

    float acc = 0.0f;

    ISSUE_SLOT(0)
    ISSUE_SLOT(1)            // 14 outstanding

    WAITV(7)                 // slot0 complete
    COMPUTE_SLOT(0)
    FENCE()
    ISSUE_SLOT(2)            // 14 outstanding

    WAITV(7)                 // slot1 complete
    COMPUTE_SLOT(1)
    FENCE()
    ISSUE_SLOT(3)            // 14 outstanding

    WAITV(7)                 // slot2 complete
    COMPUTE_SLOT(2)

    WAITV(0)                 // slot3 complete
    COMPUTE_SLOT(3)

    // wave/block reduce (acc nonzero at lanes 0 and 32)
    acc += __shfl_xor(acc, 32);
    if (lane == 0) swave[wid] = acc;
    __syncthreads();
    if (tid == 0) {
        block_sums[blockIdx.x] = swave[0] + swave[1] + swave[2] + swave[3];
    }
}

__global__ __launch_bounds__(1024) void g2v_final(
    const float* __restrict__ block_sums, int n, float* __restrict__ out)
{
    __shared__ float s[1024];
    float t = 0.0f;
    for (int i = threadIdx.x; i < n; i += 1024) t += block_sums[i];
    s[threadIdx.x] = t;
    __syncthreads();
    for (int w = 512; w > 0; w >>= 1) {
        if (threadIdx.x < w) s[threadIdx.x] += s[threadIdx.x + w];
        __syncthreads();
    }
    if (threadIdx.x == 0) out[0] = -s[0] / (float)BATCH;
}

extern "C" void kernel_launch(void* const* d_in, const int* in_sizes, int n_in,
                              void* d_out, int out_size, void* d_ws, size_t ws_size,
                              hipStream_t stream) {
    const float* W_in         = (const float*)d_in[0];
    const float* W_ctx        = (const float*)d_in[1];
    const int*   input_word   = (const int*)d_in[2];
    const int*   context_word = (const int*)d_in[3];
    const int*   neg_idx      = (const int*)d_in[4];

    float* block_sums = (float*)d_ws;   // BLOCKS floats
    float* out        = (float*)d_out;

    g2v_partial<<<BLOCKS, TPB, 0, stream>>>(W_in, W_ctx, input_word,
                                            context_word, neg_idx, block_sums);
    g2v_final<<<1, 1024, 0, stream>>>(block_sums, BLOCKS, out);
}

// Round 6
// 44.811 us; speedup vs baseline: 1.5123x; 1.5123x over previous
//
#include <hip/hip_runtime.h>

#define VOCAB 100000
#define DIM 128
#define BATCH 65536
#define NEG 5

#define TPB 256
#define GRPS_PER_BLK (TPB / 16)            // 16 lanes per element
#define BLOCKS (BATCH / GRPS_PER_BLK)      // 4096 -> exactly 1 element per group

__device__ __forceinline__ float log_sigmoid(float x) {
    return fminf(x, 0.0f) - log1pf(expf(-fabsf(x)));
}

__device__ __forceinline__ float dot4(float4 a, float4 b) {
    return a.x * b.x + a.y * b.y + a.z * b.z + a.w * b.w;
}

__global__ __launch_bounds__(TPB) void g2v_partial(
    const float* __restrict__ W_in, const float* __restrict__ W_ctx,
    const int* __restrict__ input_word, const int* __restrict__ context_word,
    const int* __restrict__ neg_idx, float* __restrict__ block_sums)
{
    const int lane16 = threadIdx.x & 15;
    const int grp_in_blk = threadIdx.x >> 4;
    const int b = blockIdx.x * GRPS_PER_BLK + grp_in_blk;   // one element per group

    const float4* __restrict__ W_in4 = (const float4*)W_in;
    const float4* __restrict__ W_ctx4 = (const float4*)W_ctx;

    const int iw = input_word[b];
    const int cw = context_word[b];
    int nw[NEG];
    #pragma unroll
    for (int k = 0; k < NEG; ++k) nw[k] = neg_idx[b * NEG + k];

    // row = 128 floats = 32 float4; lane16 covers 2 float4 (stride 16)
    const float4* ri = W_in4 + iw * 32 + lane16;
    const float4 ei0 = ri[0];
    const float4 ei1 = ri[16];

    const float4* rc = W_ctx4 + cw * 32 + lane16;
    const float4 ec0 = rc[0];
    const float4 ec1 = rc[16];

    float4 en0[NEG], en1[NEG];
    #pragma unroll
    for (int k = 0; k < NEG; ++k) {
        const float4* rn = W_in4 + nw[k] * 32 + lane16;
        en0[k] = rn[0];
        en1[k] = rn[16];
    }

    float pos = dot4(ei0, ec0) + dot4(ei1, ec1);
    float nd[NEG];
    #pragma unroll
    for (int k = 0; k < NEG; ++k)
        nd[k] = dot4(en0[k], ei0) + dot4(en1[k], ei1);

    // butterfly reduce within each 16-lane group (masks 1,2,4,8)
    #pragma unroll
    for (int m = 1; m <= 8; m <<= 1) {
        pos += __shfl_xor(pos, m);
        #pragma unroll
        for (int k = 0; k < NEG; ++k) nd[k] += __shfl_xor(nd[k], m);
    }

    float loss = 0.0f;
    if (lane16 == 0) {
        loss = log_sigmoid(pos);
        #pragma unroll
        for (int k = 0; k < NEG; ++k) loss += log_sigmoid(-nd[k]);
    }

    __shared__ float s[GRPS_PER_BLK];
    if (lane16 == 0) s[grp_in_blk] = loss;
    __syncthreads();
    if (threadIdx.x == 0) {
        float t = 0.0f;
        #pragma unroll
        for (int i = 0; i < GRPS_PER_BLK; ++i) t += s[i];
        block_sums[blockIdx.x] = t;
    }
}

__global__ __launch_bounds__(1024) void g2v_final(
    const float* __restrict__ block_sums, int n, float* __restrict__ out)
{
    __shared__ float s[1024];
    float t = 0.0f;
    for (int i = threadIdx.x; i < n; i += 1024) t += block_sums[i];
    s[threadIdx.x] = t;
    __syncthreads();
    for (int w = 512; w > 0; w >>= 1) {
        if (threadIdx.x < w) s[threadIdx.x] += s[threadIdx.x + w];
        __syncthreads();
    }
    if (threadIdx.x == 0) out[0] = -s[0] / (float)BATCH;
}

extern "C" void kernel_launch(void* const* d_in, const int* in_sizes, int n_in,
                              void* d_out, int out_size, void* d_ws, size_t ws_size,
                              hipStream_t stream) {
    const float* W_in        = (const float*)d_in[0];
    const float* W_ctx       = (const float*)d_in[1];
    const int*   input_word  = (const int*)d_in[2];
    const int*   context_word= (const int*)d_in[3];
    const int*   neg_idx     = (const int*)d_in[4];

    float* block_sums = (float*)d_ws;   // BLOCKS floats
    float* out        = (float*)d_out;

    g2v_partial<<<BLOCKS, TPB, 0, stream>>>(W_in, W_ctx, input_word,
                                            context_word, neg_idx, block_sums);
    g2v_final<<<1, 1024, 0, stream>>>(block_sums, BLOCKS, out);
}